// Round 5
// baseline (101.325 us; speedup 1.0000x reference)
//
#include <hip/hip_runtime.h>
#include <cstdint>

typedef unsigned short u16;
typedef __bf16 bf16x8 __attribute__((ext_vector_type(8)));
typedef float f32x4 __attribute__((ext_vector_type(4)));
typedef u16 u16x4 __attribute__((ext_vector_type(4)));
typedef u16 u16x8 __attribute__((ext_vector_type(8)));

static __device__ __forceinline__ u16 f2bf(float f) {
  return __builtin_bit_cast(u16, (__bf16)f);
}
static __device__ __forceinline__ float fexp2(float x) {
  float r;
  asm("v_exp_f32 %0, %1" : "=v"(r) : "v"(x));   // bare 2^x, 1 instr; exact for |x|<8
  return r;
}

#define GLOAD16(gsrc, ldst) \
  __builtin_amdgcn_global_load_lds((const __attribute__((address_space(1))) void*)(gsrc), \
                                   (__attribute__((address_space(3))) void*)(ldst), 16, 0, 0)

// B=2, T=2048, D=1024, H=16, HD=64, 3D=3072, M=B*T=4096
// ws layout (bytes):
//   xbf  @ 0         : 4096*1024*2   = 8388608
//   Wt   @ 8388608   : 3072*1024*2   = 6291456
//   qkv  @ 14680064  : 4096*3072*2   = 25165824   (q columns pre-scaled by 0.125*log2e)
//   vT   @ 39845888  : 32*64*2048*2  = 8388608    (total 48234496)

// ---------------- kernel 1: x fp32->bf16 convert + W transpose (fused) ----------------
__global__ __launch_bounds__(256) void k_prep(const float* __restrict__ x,
                                              const float* __restrict__ W,
                                              u16* __restrict__ xbf,
                                              u16* __restrict__ Wt) {
  __shared__ __align__(16) u16 tile[64 * 72];
  int t = threadIdx.x;
  if (blockIdx.x < 2048) {
    int idx = blockIdx.x * 256 + t;                // 524288 threads * 8 elems
    const float4* xv = (const float4*)x;
    float4 a = xv[(size_t)idx * 2];
    float4 b = xv[(size_t)idx * 2 + 1];
    u16x8 o;
    o[0]=f2bf(a.x); o[1]=f2bf(a.y); o[2]=f2bf(a.z); o[3]=f2bf(a.w);
    o[4]=f2bf(b.x); o[5]=f2bf(b.y); o[6]=f2bf(b.z); o[7]=f2bf(b.w);
    *(u16x8*)(xbf + (size_t)idx * 8) = o;
    return;
  }
  int bid = blockIdx.x - 2048;
  int bk = bid & 15, bn = bid >> 4;                // 16 k-tiles x 48 n-tiles
  int k0 = bk * 64, n0 = bn * 64;
  #pragma unroll
  for (int r = 0; r < 4; r++) {
    int id = r * 256 + t;                          // 0..1023
    int kl = id >> 4;
    int c  = (id & 15) * 4;
    float4 v = *(const float4*)(W + (size_t)(k0 + kl) * 3072 + n0 + c);
    u16x4 o; o[0]=f2bf(v.x); o[1]=f2bf(v.y); o[2]=f2bf(v.z); o[3]=f2bf(v.w);
    *(u16x4*)(tile + kl * 72 + c) = o;
  }
  __syncthreads();
  #pragma unroll
  for (int r = 0; r < 2; r++) {
    int id = r * 256 + t;                          // 0..511
    int nl = id >> 3;
    int w  = id & 7;                               // 16B chunk = 8 k
    u16x8 o;
    #pragma unroll
    for (int i = 0; i < 8; i++) o[i] = tile[(w * 8 + i) * 72 + nl];
    *(u16x8*)(Wt + (size_t)(n0 + nl) * 1024 + k0 + w * 8) = o;
  }
}

// ------- kernel 2: qkv = xbf @ Wt^T + b  (bf16 MFMA, 256x192x32 tiles) -------
// 8 waves (2M x 4N), wave = 128x48 output. Double-buffered LDS with 1-tile
// staging lookahead and ONE __syncthreads per K-tile (issue-to-drain ~1 tile).
// q columns (col<1024) pre-scaled by 0.125*log2e for the attention exp2 domain.
// Also dual-writes v-columns transposed into vT[b][h][d][t].
__global__ __launch_bounds__(512, 2) void k_gemm_qkv(const u16* __restrict__ xbf,
                                                     const u16* __restrict__ wt,
                                                     const float* __restrict__ bias,
                                                     u16* __restrict__ qkv,
                                                     u16* __restrict__ vT) {
  __shared__ __align__(16) u16 As[2 * 256 * 32];   // 32 KB (2 bufs x 16KB)
  __shared__ __align__(16) u16 Bs[2 * 192 * 32];   // 24 KB (2 bufs x 12KB)
  int wg = blockIdx.x;
  int swz = (wg & 7) * 32 + (wg >> 3);             // XCD-aware, bijective (256 = 8*32)
  int mt = swz >> 4, nt = swz & 15;                // 16 m-tiles x 16 n-tiles
  int m0 = mt * 256, n0 = nt * 192;
  int t = threadIdx.x;                             // 0..511
  int lane = t & 63, wid = t >> 6;
  int wm = wid >> 2, wn = wid & 3;
  int g = lane >> 4, li = lane & 15;

  f32x4 acc[8][3];
  #pragma unroll
  for (int i = 0; i < 8; i++)
    #pragma unroll
    for (int j = 0; j < 3; j++) acc[i][j] = (f32x4){0.f, 0.f, 0.f, 0.f};

  // staging: rows of 32 k = 64B = 4 units of 16B; phys unit w holds logical w^(row&3)
  auto stage = [&](int kt, int buf) {
    char* ad = (char*)As + buf * 16384;
    char* bd = (char*)Bs + buf * 12288;
    #pragma unroll
    for (int i = 0; i < 2; i++) {
      int p = t + i * 512;                         // 0..1023 (A: 256 rows x 4 units)
      int row = p >> 2, ug = (p & 3) ^ (row & 3);
      GLOAD16(xbf + (size_t)(m0 + row) * 1024 + kt * 32 + ug * 8, ad + p * 16);
    }
    #pragma unroll
    for (int i = 0; i < 2; i++) {
      int p = t + i * 512;                         // B: 768 units (192 rows x 4)
      if (p < 768) {
        int row = p >> 2, ug = (p & 3) ^ (row & 3);
        GLOAD16(wt + (size_t)(n0 + row) * 1024 + kt * 32 + ug * 8, bd + p * 16);
      }
    }
  };

  stage(0, 0);
  for (int kt = 0; kt < 32; ++kt) {
    __syncthreads();                               // drains tile-kt loads (issued ~1 tile ago)
    if (kt < 31) stage(kt + 1, (kt & 1) ^ 1);
    const char* ab = (const char*)As + (kt & 1) * 16384;
    const char* bb = (const char*)Bs + (kt & 1) * 12288;

    bf16x8 af[8], bfr[3];
    #pragma unroll
    for (int mi = 0; mi < 8; mi++) {
      int row = wm * 128 + mi * 16 + li;
      int u = g ^ (row & 3);
      af[mi] = *(const bf16x8*)(ab + row * 64 + u * 16);
    }
    #pragma unroll
    for (int ni = 0; ni < 3; ni++) {
      int row = wn * 48 + ni * 16 + li;
      int u = g ^ (row & 3);
      bfr[ni] = *(const bf16x8*)(bb + row * 64 + u * 16);
    }
    __builtin_amdgcn_s_setprio(1);
    #pragma unroll
    for (int mi = 0; mi < 8; mi++)
      #pragma unroll
      for (int ni = 0; ni < 3; ni++)
        acc[mi][ni] = __builtin_amdgcn_mfma_f32_16x16x32_bf16(af[mi], bfr[ni], acc[mi][ni], 0, 0, 0);
    __builtin_amdgcn_s_setprio(0);
  }

  // epilogue: +bias, scale q-cols, ->bf16; q/k cols -> qkv; v cols -> vT transposed
  int b = m0 >> 11;              // batch (M-tile never crosses batch: 2048%256==0)
  int tbase = m0 & 2047;
  #pragma unroll
  for (int ni = 0; ni < 3; ni++) {
    int col = n0 + wn * 48 + ni * 16 + li;
    float bv = bias[col];
    float sc = (col < 1024) ? 0.18033688011112042f : 1.0f;  // 0.125*log2(e) on q
    #pragma unroll
    for (int mi = 0; mi < 8; mi++) {
      int trow = tbase + wm * 128 + mi * 16 + g * 4;
      if (col < 2048) {
        #pragma unroll
        for (int j = 0; j < 4; j++) {
          float v = (acc[mi][ni][j] + bv) * sc;
          qkv[(size_t)(b * 2048 + trow + j) * 3072 + col] = f2bf(v);
        }
      } else {
        u16x4 o;
        #pragma unroll
        for (int j = 0; j < 4; j++) o[j] = f2bf(acc[mi][ni][j] + bv);
        // vT[b][h][d][t] with h*64+d = col-2048; 4 consecutive t
        *(u16x4*)(vT + ((size_t)(b * 1024 + (col - 2048))) * 2048 + trow) = o;
      }
    }
  }
}

// ------- kernel 3: flash attention, 32 q/wave, static softmax -------
// 128-key phases (2 x 64-key halves), 64KB double-buffered LDS, permuted-key K
// staging (P packs lane-locally, V reads are single swizzled b128), bare
// v_exp_f32, lsum on the MFMA pipe (all-ones A fragment). Cross-half ILP:
// QK^T for BOTH halves first (S in regs), then per half {exp,pack,PV} so
// half-1's VALU overlaps half-0's PV MFMAs.
__global__ __launch_bounds__(256, 2) void k_attn(const u16* __restrict__ qkv,
                                                 const u16* __restrict__ vT,
                                                 float* __restrict__ out) {
  // LDS bytes: K0 @0, K1 @16384, V0 @32768, V1 @49152. Epilogue reuses [0,32768).
  __shared__ __align__(16) u16 smem[32768];        // 64 KB
  int bid = blockIdx.x;
  int qt = bid & 15, bh = bid >> 4;                // 16 q-tiles (128 q) x 32 bh
  int b = bh >> 4, h = bh & 15;
  int qbase = qt * 128;
  int t = threadIdx.x, lane = t & 63, wave = t >> 6;
  int g = lane >> 4, li = lane & 15;

  // Q fragments: 2 x 16 q-rows per wave (pre-scaled by 0.125*log2e in GEMM)
  size_t qrowa = (size_t)(b * 2048 + qbase + wave * 32 + li) * 3072 + h * 64;
  bf16x8 qa0 = *(const bf16x8*)(qkv + qrowa + g * 8);
  bf16x8 qa1 = *(const bf16x8*)(qkv + qrowa + 32 + g * 8);
  bf16x8 qb0 = *(const bf16x8*)(qkv + qrowa + 16 * 3072 + g * 8);
  bf16x8 qb1 = *(const bf16x8*)(qkv + qrowa + 16 * 3072 + 32 + g * 8);

  // all-ones bf16 A-fragment for MFMA-side lsum
  u16x8 ob;
  #pragma unroll
  for (int i = 0; i < 8; i++) ob[i] = 0x3F80;
  bf16x8 ones = __builtin_bit_cast(bf16x8, ob);

  f32x4 o[2][4];
  #pragma unroll
  for (int f = 0; f < 2; f++)
    #pragma unroll
    for (int i = 0; i < 4; i++) o[f][i] = (f32x4){0.f, 0.f, 0.f, 0.f};
  f32x4 la = (f32x4){0.f, 0.f, 0.f, 0.f}, lb = la;  // lsum accumulators (MFMA)

  const u16* kbase_g = qkv + (size_t)(b * 2048) * 3072 + 1024 + h * 64;
  const u16* vbase_g = vT + (size_t)(bh * 64) * 2048;

  // staging slots (loop-invariant). K: 128 rows x 128B; V: 64 rows x 256B.
  // K rows permuted: kperm7(r) = (r&96) | ((r&16)>>2) | (((r>>2)&3)<<3) | (r&3)
  int kRow[4], kUg[4], vRow[4], vUg[4];
  #pragma unroll
  for (int i = 0; i < 4; i++) {
    int p = t + i * 256;
    int kr = p >> 3;
    kRow[i] = (kr & 96) | ((kr & 16) >> 2) | (((kr >> 2) & 3) << 3) | (kr & 3);
    kUg[i] = (p & 7) ^ (kr & 7);
    int vd = p >> 4;
    vRow[i] = vd;
    vUg[i] = (p & 15) ^ (vd & 7);
  }

  auto stage = [&](int key0, int buf) {
    char* kd = (char*)smem + buf * 16384;
    char* vd_ = (char*)smem + 32768 + buf * 16384;
    #pragma unroll
    for (int i = 0; i < 4; i++) {
      int p = t + i * 256;
      GLOAD16(kbase_g + (size_t)(key0 + kRow[i]) * 3072 + kUg[i] * 8, kd + p * 16);
      GLOAD16(vbase_g + (size_t)vRow[i] * 2048 + key0 + vUg[i] * 8, vd_ + p * 16);
    }
  };

  stage(0, 0);
  asm volatile("s_waitcnt vmcnt(0)" ::: "memory");
  __syncthreads();

  #pragma unroll 2
  for (int ph = 0; ph < 16; ++ph) {
    int buf = ph & 1;
    const char* kb = (const char*)smem + buf * 16384;
    const char* vb = (const char*)smem + 32768 + buf * 16384;

    if (ph < 15) stage((ph + 1) * 128, buf ^ 1);   // lands by end-of-phase barrier

    // --- QK^T for BOTH halves; S stays in registers ---
    f32x4 sa[2][4], sb[2][4];
    int u0 = g ^ (li & 7);
    __builtin_amdgcn_s_setprio(1);
    #pragma unroll
    for (int h2 = 0; h2 < 2; ++h2) {
      const char* kbh = kb + h2 * 8192;
      #pragma unroll
      for (int st = 0; st < 4; ++st) {
        bf16x8 kf0 = *(const bf16x8*)(kbh + (st * 16 + li) * 128 + u0 * 16);
        bf16x8 kf1 = *(const bf16x8*)(kbh + (st * 16 + li) * 128 + (u0 ^ 4) * 16);
        f32x4 z = (f32x4){0.f, 0.f, 0.f, 0.f};
        sa[h2][st] = __builtin_amdgcn_mfma_f32_16x16x32_bf16(kf0, qa0, z, 0, 0, 0);
        sa[h2][st] = __builtin_amdgcn_mfma_f32_16x16x32_bf16(kf1, qa1, sa[h2][st], 0, 0, 0);
        sb[h2][st] = __builtin_amdgcn_mfma_f32_16x16x32_bf16(kf0, qb0, z, 0, 0, 0);
        sb[h2][st] = __builtin_amdgcn_mfma_f32_16x16x32_bf16(kf1, qb1, sb[h2][st], 0, 0, 0);
      }
    }
    __builtin_amdgcn_s_setprio(0);

    // --- per half: exp (VALU) -> pack -> lsum+PV (MFMA). half-1 VALU overlaps
    //     half-0 PV MFMAs (independent). ---
    #pragma unroll
    for (int h2 = 0; h2 < 2; ++h2) {
      float pa[16], pbf[16];
      #pragma unroll
      for (int i = 0; i < 16; i++) pa[i] = fexp2(sa[h2][i >> 2][i & 3]);
      #pragma unroll
      for (int i = 0; i < 16; i++) pbf[i] = fexp2(sb[h2][i >> 2][i & 3]);

      // pack P fragments: kperm makes elem e of chunk c = physical key c*32+g*8+e
      bf16x8 pba[2], pbb[2];
      #pragma unroll
      for (int c = 0; c < 2; c++)
        #pragma unroll
        for (int e = 0; e < 8; e++) {
          pba[c][e] = (__bf16)pa[c * 8 + e];
          pbb[c][e] = (__bf16)pbf[c * 8 + e];
        }

      __builtin_amdgcn_s_setprio(1);
      la = __builtin_amdgcn_mfma_f32_16x16x32_bf16(ones, pba[0], la, 0, 0, 0);
      la = __builtin_amdgcn_mfma_f32_16x16x32_bf16(ones, pba[1], la, 0, 0, 0);
      lb = __builtin_amdgcn_mfma_f32_16x16x32_bf16(ones, pbb[0], lb, 0, 0, 0);
      lb = __builtin_amdgcn_mfma_f32_16x16x32_bf16(ones, pbb[1], lb, 0, 0, 0);
      #pragma unroll
      for (int c = 0; c < 2; c++) {
        int ucb = h2 * 8 + c * 4 + g;
        #pragma unroll
        for (int dt = 0; dt < 4; dt++) {
          int d = dt * 16 + li;
          bf16x8 vf = *(const bf16x8*)(vb + d * 256 + ((ucb ^ (li & 7)) << 4));
          o[0][dt] = __builtin_amdgcn_mfma_f32_16x16x32_bf16(vf, pba[c], o[0][dt], 0, 0, 0);
          o[1][dt] = __builtin_amdgcn_mfma_f32_16x16x32_bf16(vf, pbb[c], o[1][dt], 0, 0, 0);
        }
      }
      __builtin_amdgcn_s_setprio(0);
    }

    __syncthreads();   // drains vmcnt (next-phase stage) + lgkm; one barrier per 128 keys
  }

  // epilogue: every lane already holds its q-column's full lsum in la[0]/lb[0]
  float inva = 1.0f / la[0], invb = 1.0f / lb[0];
  #pragma unroll
  for (int f = 0; f < 2; f++) {
    float inv = f ? invb : inva;
    int ql = wave * 32 + f * 16 + li;
    #pragma unroll
    for (int dt = 0; dt < 4; dt++) {
      int u = dt * 4 + g;
      int up = u ^ (ql & 7);
      f32x4 v = o[f][dt] * inv;
      *(f32x4*)((char*)smem + ql * 256 + up * 16) = v;
    }
  }
  __syncthreads();
  int ql = t >> 1, seg = t & 1;
  size_t obase = (size_t)(b * 2048 + qbase + ql) * 1024 + h * 64;
  #pragma unroll
  for (int i = 0; i < 8; i++) {
    int u = seg * 8 + i;
    int up = u ^ (ql & 7);
    f32x4 v = *(const f32x4*)((const char*)smem + ql * 256 + up * 16);
    *(f32x4*)(out + obase + u * 4) = v;
  }
}

extern "C" void kernel_launch(void* const* d_in, const int* in_sizes, int n_in,
                              void* d_out, int out_size, void* d_ws, size_t ws_size,
                              hipStream_t stream) {
  const float* x    = (const float*)d_in[0];
  const float* W    = (const float*)d_in[1];
  const float* bias = (const float*)d_in[2];
  float* out = (float*)d_out;
  char* ws = (char*)d_ws;
  u16* xbf = (u16*)(ws + 0);
  u16* wt  = (u16*)(ws + 8388608);
  u16* qkv = (u16*)(ws + 14680064);
  u16* vt  = (u16*)(ws + 39845888);

  k_prep<<<2816, 256, 0, stream>>>(x, W, xbf, wt);
  k_gemm_qkv<<<256, 512, 0, stream>>>(xbf, wt, bias, qkv, vt);
  k_attn<<<512, 256, 0, stream>>>(qkv, vt, out);
}

// Round 6
// 93.562 us; speedup vs baseline: 1.0830x; 1.0830x over previous
//
#include <hip/hip_runtime.h>
#include <cstdint>

typedef unsigned short u16;
typedef __bf16 bf16x8 __attribute__((ext_vector_type(8)));
typedef float f32x4 __attribute__((ext_vector_type(4)));
typedef u16 u16x4 __attribute__((ext_vector_type(4)));
typedef u16 u16x8 __attribute__((ext_vector_type(8)));

static __device__ __forceinline__ u16 f2bf(float f) {
  return __builtin_bit_cast(u16, (__bf16)f);
}
static __device__ __forceinline__ float fexp2(float x) {
  float r;
  asm("v_exp_f32 %0, %1" : "=v"(r) : "v"(x));   // bare 2^x, 1 instr; exact for |x|<8
  return r;
}

#define GLOAD16(gsrc, ldst) \
  __builtin_amdgcn_global_load_lds((const __attribute__((address_space(1))) void*)(gsrc), \
                                   (__attribute__((address_space(3))) void*)(ldst), 16, 0, 0)

// B=2, T=2048, D=1024, H=16, HD=64, 3D=3072, M=B*T=4096
// ws layout (bytes):
//   xbf  @ 0         : 4096*1024*2   = 8388608
//   Wt   @ 8388608   : 3072*1024*2   = 6291456
//   qkv  @ 14680064  : 4096*3072*2   = 25165824   (q columns pre-scaled by 0.125*log2e)
//   vT   @ 39845888  : 32*64*2048*2  = 8388608    (total 48234496)

// ---------------- kernel 1: x fp32->bf16 convert + W transpose (fused) ----------------
__global__ __launch_bounds__(256) void k_prep(const float* __restrict__ x,
                                              const float* __restrict__ W,
                                              u16* __restrict__ xbf,
                                              u16* __restrict__ Wt) {
  __shared__ __align__(16) u16 tile[64 * 72];
  int t = threadIdx.x;
  if (blockIdx.x < 2048) {
    int idx = blockIdx.x * 256 + t;                // 524288 threads * 8 elems
    const float4* xv = (const float4*)x;
    float4 a = xv[(size_t)idx * 2];
    float4 b = xv[(size_t)idx * 2 + 1];
    u16x8 o;
    o[0]=f2bf(a.x); o[1]=f2bf(a.y); o[2]=f2bf(a.z); o[3]=f2bf(a.w);
    o[4]=f2bf(b.x); o[5]=f2bf(b.y); o[6]=f2bf(b.z); o[7]=f2bf(b.w);
    *(u16x8*)(xbf + (size_t)idx * 8) = o;
    return;
  }
  int bid = blockIdx.x - 2048;
  int bk = bid & 15, bn = bid >> 4;                // 16 k-tiles x 48 n-tiles
  int k0 = bk * 64, n0 = bn * 64;
  #pragma unroll
  for (int r = 0; r < 4; r++) {
    int id = r * 256 + t;                          // 0..1023
    int kl = id >> 4;
    int c  = (id & 15) * 4;
    float4 v = *(const float4*)(W + (size_t)(k0 + kl) * 3072 + n0 + c);
    u16x4 o; o[0]=f2bf(v.x); o[1]=f2bf(v.y); o[2]=f2bf(v.z); o[3]=f2bf(v.w);
    *(u16x4*)(tile + kl * 72 + c) = o;
  }
  __syncthreads();
  #pragma unroll
  for (int r = 0; r < 2; r++) {
    int id = r * 256 + t;                          // 0..511
    int nl = id >> 3;
    int w  = id & 7;                               // 16B chunk = 8 k
    u16x8 o;
    #pragma unroll
    for (int i = 0; i < 8; i++) o[i] = tile[(w * 8 + i) * 72 + nl];
    *(u16x8*)(Wt + (size_t)(n0 + nl) * 1024 + k0 + w * 8) = o;
  }
}

// ------- kernel 2: qkv = xbf @ Wt^T + b  (bf16 MFMA, 128x192x32 tiles) -------
// 4 waves (2M x 2N), wave = 64x96 output (acc 4x6). Double-buffered LDS, ONE
// __syncthreads per K-tile, 1-tile staging lookahead. 512 blocks = 2-3/CU so
// inter-block wave overlap hides the staging drain (m114 mechanism).
// LDS row = 32 k = 64B = 4 units; swizzle f(row)=(row>>1)&3 (bank-exact for
// 64B rows: row parity supplies the 16-bank offset, f spreads the 4 units).
// q columns (col<1024) pre-scaled by 0.125*log2e for the attention exp2 domain.
// Also dual-writes v-columns transposed into vT[b][h][d][t].
__global__ __launch_bounds__(256, 3) void k_gemm_qkv(const u16* __restrict__ xbf,
                                                     const u16* __restrict__ wt,
                                                     const float* __restrict__ bias,
                                                     u16* __restrict__ qkv,
                                                     u16* __restrict__ vT) {
  __shared__ __align__(16) u16 As[2 * 128 * 32];   // 16 KB (2 bufs x 8KB)
  __shared__ __align__(16) u16 Bs[2 * 192 * 32];   // 24 KB (2 bufs x 12KB)
  int wg = blockIdx.x;
  int swz = (wg & 7) * 64 + (wg >> 3);             // XCD-aware, bijective (512 = 8*64)
  int mt = swz >> 4, nt = swz & 15;                // 32 m-tiles x 16 n-tiles
  int m0 = mt * 128, n0 = nt * 192;
  int t = threadIdx.x;                             // 0..255
  int lane = t & 63, wid = t >> 6;
  int wm = wid >> 1, wn = wid & 1;
  int g = lane >> 4, li = lane & 15;

  f32x4 acc[4][6];
  #pragma unroll
  for (int i = 0; i < 4; i++)
    #pragma unroll
    for (int j = 0; j < 6; j++) acc[i][j] = (f32x4){0.f, 0.f, 0.f, 0.f};

  // staging: phys unit w holds global unit w^((row>>1)&3)
  auto stage = [&](int kt, int buf) {
    char* ad = (char*)As + buf * 8192;
    char* bd = (char*)Bs + buf * 12288;
    #pragma unroll
    for (int i = 0; i < 2; i++) {
      int p = t + i * 256;                         // A: 128 rows x 4 units = 512
      int row = p >> 2, ug = (p & 3) ^ ((row >> 1) & 3);
      GLOAD16(xbf + (size_t)(m0 + row) * 1024 + kt * 32 + ug * 8, ad + p * 16);
    }
    #pragma unroll
    for (int i = 0; i < 3; i++) {
      int p = t + i * 256;                         // B: 192 rows x 4 units = 768
      int row = p >> 2, ug = (p & 3) ^ ((row >> 1) & 3);
      GLOAD16(wt + (size_t)(n0 + row) * 1024 + kt * 32 + ug * 8, bd + p * 16);
    }
  };

  stage(0, 0);
  for (int kt = 0; kt < 32; ++kt) {
    __syncthreads();                               // drains tile-kt loads (issued 1 tile ago)
    if (kt < 31) stage(kt + 1, (kt & 1) ^ 1);
    const char* ab = (const char*)As + (kt & 1) * 8192;
    const char* bb = (const char*)Bs + (kt & 1) * 12288;

    bf16x8 af[4], bfr[6];
    #pragma unroll
    for (int mi = 0; mi < 4; mi++) {
      int row = wm * 64 + mi * 16 + li;
      int u = g ^ ((row >> 1) & 3);
      af[mi] = *(const bf16x8*)(ab + row * 64 + u * 16);
    }
    #pragma unroll
    for (int ni = 0; ni < 6; ni++) {
      int row = wn * 96 + ni * 16 + li;
      int u = g ^ ((row >> 1) & 3);
      bfr[ni] = *(const bf16x8*)(bb + row * 64 + u * 16);
    }
    __builtin_amdgcn_s_setprio(1);
    #pragma unroll
    for (int mi = 0; mi < 4; mi++)
      #pragma unroll
      for (int ni = 0; ni < 6; ni++)
        acc[mi][ni] = __builtin_amdgcn_mfma_f32_16x16x32_bf16(af[mi], bfr[ni], acc[mi][ni], 0, 0, 0);
    __builtin_amdgcn_s_setprio(0);
  }

  // epilogue: +bias, scale q-cols, ->bf16; q/k cols -> qkv; v cols -> vT transposed
  int b = m0 >> 11;              // batch (M-tile never crosses batch: 2048%128==0)
  int tbase = m0 & 2047;
  #pragma unroll
  for (int ni = 0; ni < 6; ni++) {
    int col = n0 + wn * 96 + ni * 16 + li;
    float bv = bias[col];
    float sc = (col < 1024) ? 0.18033688011112042f : 1.0f;  // 0.125*log2(e) on q
    #pragma unroll
    for (int mi = 0; mi < 4; mi++) {
      int trow = tbase + wm * 64 + mi * 16 + g * 4;
      if (col < 2048) {
        #pragma unroll
        for (int j = 0; j < 4; j++) {
          float v = (acc[mi][ni][j] + bv) * sc;
          qkv[(size_t)(b * 2048 + trow + j) * 3072 + col] = f2bf(v);
        }
      } else {
        u16x4 o;
        #pragma unroll
        for (int j = 0; j < 4; j++) o[j] = f2bf(acc[mi][ni][j] + bv);
        // vT[b][h][d][t] with h*64+d = col-2048; 4 consecutive t
        *(u16x4*)(vT + ((size_t)(b * 1024 + (col - 2048))) * 2048 + trow) = o;
      }
    }
  }
}

// ------- kernel 3: flash attention, 32 q/wave, static softmax -------
// 128-key phases (2 x 64-key halves), 64KB double-buffered LDS, permuted-key K
// staging (P packs lane-locally, V reads are single swizzled b128), bare
// v_exp_f32, lsum on the MFMA pipe (all-ones A fragment). Cross-half ILP:
// QK^T for BOTH halves first (S in regs), then per half {exp,pack,PV} so
// half-1's VALU overlaps half-0's PV MFMAs.
__global__ __launch_bounds__(256, 2) void k_attn(const u16* __restrict__ qkv,
                                                 const u16* __restrict__ vT,
                                                 float* __restrict__ out) {
  // LDS bytes: K0 @0, K1 @16384, V0 @32768, V1 @49152. Epilogue reuses [0,32768).
  __shared__ __align__(16) u16 smem[32768];        // 64 KB
  int bid = blockIdx.x;
  int qt = bid & 15, bh = bid >> 4;                // 16 q-tiles (128 q) x 32 bh
  int b = bh >> 4, h = bh & 15;
  int qbase = qt * 128;
  int t = threadIdx.x, lane = t & 63, wave = t >> 6;
  int g = lane >> 4, li = lane & 15;

  // Q fragments: 2 x 16 q-rows per wave (pre-scaled by 0.125*log2e in GEMM)
  size_t qrowa = (size_t)(b * 2048 + qbase + wave * 32 + li) * 3072 + h * 64;
  bf16x8 qa0 = *(const bf16x8*)(qkv + qrowa + g * 8);
  bf16x8 qa1 = *(const bf16x8*)(qkv + qrowa + 32 + g * 8);
  bf16x8 qb0 = *(const bf16x8*)(qkv + qrowa + 16 * 3072 + g * 8);
  bf16x8 qb1 = *(const bf16x8*)(qkv + qrowa + 16 * 3072 + 32 + g * 8);

  // all-ones bf16 A-fragment for MFMA-side lsum
  u16x8 ob;
  #pragma unroll
  for (int i = 0; i < 8; i++) ob[i] = 0x3F80;
  bf16x8 ones = __builtin_bit_cast(bf16x8, ob);

  f32x4 o[2][4];
  #pragma unroll
  for (int f = 0; f < 2; f++)
    #pragma unroll
    for (int i = 0; i < 4; i++) o[f][i] = (f32x4){0.f, 0.f, 0.f, 0.f};
  f32x4 la = (f32x4){0.f, 0.f, 0.f, 0.f}, lb = la;  // lsum accumulators (MFMA)

  const u16* kbase_g = qkv + (size_t)(b * 2048) * 3072 + 1024 + h * 64;
  const u16* vbase_g = vT + (size_t)(bh * 64) * 2048;

  // staging slots (loop-invariant). K: 128 rows x 128B; V: 64 rows x 256B.
  // K rows permuted: kperm7(r) = (r&96) | ((r&16)>>2) | (((r>>2)&3)<<3) | (r&3)
  int kRow[4], kUg[4], vRow[4], vUg[4];
  #pragma unroll
  for (int i = 0; i < 4; i++) {
    int p = t + i * 256;
    int kr = p >> 3;
    kRow[i] = (kr & 96) | ((kr & 16) >> 2) | (((kr >> 2) & 3) << 3) | (kr & 3);
    kUg[i] = (p & 7) ^ (kr & 7);
    int vd = p >> 4;
    vRow[i] = vd;
    vUg[i] = (p & 15) ^ (vd & 7);
  }

  auto stage = [&](int key0, int buf) {
    char* kd = (char*)smem + buf * 16384;
    char* vd_ = (char*)smem + 32768 + buf * 16384;
    #pragma unroll
    for (int i = 0; i < 4; i++) {
      int p = t + i * 256;
      GLOAD16(kbase_g + (size_t)(key0 + kRow[i]) * 3072 + kUg[i] * 8, kd + p * 16);
      GLOAD16(vbase_g + (size_t)vRow[i] * 2048 + key0 + vUg[i] * 8, vd_ + p * 16);
    }
  };

  stage(0, 0);
  asm volatile("s_waitcnt vmcnt(0)" ::: "memory");
  __syncthreads();

  #pragma unroll 2
  for (int ph = 0; ph < 16; ++ph) {
    int buf = ph & 1;
    const char* kb = (const char*)smem + buf * 16384;
    const char* vb = (const char*)smem + 32768 + buf * 16384;

    if (ph < 15) stage((ph + 1) * 128, buf ^ 1);   // lands by end-of-phase barrier

    // --- QK^T for BOTH halves; S stays in registers ---
    f32x4 sa[2][4], sb[2][4];
    int u0 = g ^ (li & 7);
    __builtin_amdgcn_s_setprio(1);
    #pragma unroll
    for (int h2 = 0; h2 < 2; ++h2) {
      const char* kbh = kb + h2 * 8192;
      #pragma unroll
      for (int st = 0; st < 4; ++st) {
        bf16x8 kf0 = *(const bf16x8*)(kbh + (st * 16 + li) * 128 + u0 * 16);
        bf16x8 kf1 = *(const bf16x8*)(kbh + (st * 16 + li) * 128 + (u0 ^ 4) * 16);
        f32x4 z = (f32x4){0.f, 0.f, 0.f, 0.f};
        sa[h2][st] = __builtin_amdgcn_mfma_f32_16x16x32_bf16(kf0, qa0, z, 0, 0, 0);
        sa[h2][st] = __builtin_amdgcn_mfma_f32_16x16x32_bf16(kf1, qa1, sa[h2][st], 0, 0, 0);
        sb[h2][st] = __builtin_amdgcn_mfma_f32_16x16x32_bf16(kf0, qb0, z, 0, 0, 0);
        sb[h2][st] = __builtin_amdgcn_mfma_f32_16x16x32_bf16(kf1, qb1, sb[h2][st], 0, 0, 0);
      }
    }
    __builtin_amdgcn_s_setprio(0);

    // --- per half: exp (VALU) -> pack -> lsum+PV (MFMA). half-1 VALU overlaps
    //     half-0 PV MFMAs (independent). ---
    #pragma unroll
    for (int h2 = 0; h2 < 2; ++h2) {
      float pa[16], pbf[16];
      #pragma unroll
      for (int i = 0; i < 16; i++) pa[i] = fexp2(sa[h2][i >> 2][i & 3]);
      #pragma unroll
      for (int i = 0; i < 16; i++) pbf[i] = fexp2(sb[h2][i >> 2][i & 3]);

      // pack P fragments: kperm makes elem e of chunk c = physical key c*32+g*8+e
      bf16x8 pba[2], pbb[2];
      #pragma unroll
      for (int c = 0; c < 2; c++)
        #pragma unroll
        for (int e = 0; e < 8; e++) {
          pba[c][e] = (__bf16)pa[c * 8 + e];
          pbb[c][e] = (__bf16)pbf[c * 8 + e];
        }

      __builtin_amdgcn_s_setprio(1);
      la = __builtin_amdgcn_mfma_f32_16x16x32_bf16(ones, pba[0], la, 0, 0, 0);
      la = __builtin_amdgcn_mfma_f32_16x16x32_bf16(ones, pba[1], la, 0, 0, 0);
      lb = __builtin_amdgcn_mfma_f32_16x16x32_bf16(ones, pbb[0], lb, 0, 0, 0);
      lb = __builtin_amdgcn_mfma_f32_16x16x32_bf16(ones, pbb[1], lb, 0, 0, 0);
      #pragma unroll
      for (int c = 0; c < 2; c++) {
        int ucb = h2 * 8 + c * 4 + g;
        #pragma unroll
        for (int dt = 0; dt < 4; dt++) {
          int d = dt * 16 + li;
          bf16x8 vf = *(const bf16x8*)(vb + d * 256 + ((ucb ^ (li & 7)) << 4));
          o[0][dt] = __builtin_amdgcn_mfma_f32_16x16x32_bf16(vf, pba[c], o[0][dt], 0, 0, 0);
          o[1][dt] = __builtin_amdgcn_mfma_f32_16x16x32_bf16(vf, pbb[c], o[1][dt], 0, 0, 0);
        }
      }
      __builtin_amdgcn_s_setprio(0);
    }

    __syncthreads();   // drains vmcnt (next-phase stage) + lgkm; one barrier per 128 keys
  }

  // epilogue: every lane already holds its q-column's full lsum in la[0]/lb[0]
  float inva = 1.0f / la[0], invb = 1.0f / lb[0];
  #pragma unroll
  for (int f = 0; f < 2; f++) {
    float inv = f ? invb : inva;
    int ql = wave * 32 + f * 16 + li;
    #pragma unroll
    for (int dt = 0; dt < 4; dt++) {
      int u = dt * 4 + g;
      int up = u ^ (ql & 7);
      f32x4 v = o[f][dt] * inv;
      *(f32x4*)((char*)smem + ql * 256 + up * 16) = v;
    }
  }
  __syncthreads();
  int ql = t >> 1, seg = t & 1;
  size_t obase = (size_t)(b * 2048 + qbase + ql) * 1024 + h * 64;
  #pragma unroll
  for (int i = 0; i < 8; i++) {
    int u = seg * 8 + i;
    int up = u ^ (ql & 7);
    f32x4 v = *(const f32x4*)((const char*)smem + ql * 256 + up * 16);
    *(f32x4*)(out + obase + u * 4) = v;
  }
}

extern "C" void kernel_launch(void* const* d_in, const int* in_sizes, int n_in,
                              void* d_out, int out_size, void* d_ws, size_t ws_size,
                              hipStream_t stream) {
  const float* x    = (const float*)d_in[0];
  const float* W    = (const float*)d_in[1];
  const float* bias = (const float*)d_in[2];
  float* out = (float*)d_out;
  char* ws = (char*)d_ws;
  u16* xbf = (u16*)(ws + 0);
  u16* wt  = (u16*)(ws + 8388608);
  u16* qkv = (u16*)(ws + 14680064);
  u16* vt  = (u16*)(ws + 39845888);

  k_prep<<<2816, 256, 0, stream>>>(x, W, xbf, wt);
  k_gemm_qkv<<<512, 256, 0, stream>>>(xbf, wt, bias, qkv, vt);
  k_attn<<<512, 256, 0, stream>>>(qkv, vt, out);
}

// Round 7
// 93.149 us; speedup vs baseline: 1.0878x; 1.0044x over previous
//
#include <hip/hip_runtime.h>
#include <cstdint>

typedef unsigned short u16;
typedef __bf16 bf16x8 __attribute__((ext_vector_type(8)));
typedef float f32x4 __attribute__((ext_vector_type(4)));
typedef u16 u16x4 __attribute__((ext_vector_type(4)));
typedef u16 u16x8 __attribute__((ext_vector_type(8)));

static __device__ __forceinline__ u16 f2bf(float f) {
  return __builtin_bit_cast(u16, (__bf16)f);
}
static __device__ __forceinline__ float fexp2(float x) {
  float r;
  asm("v_exp_f32 %0, %1" : "=v"(r) : "v"(x));   // bare 2^x, 1 instr; exact for |x|<8
  return r;
}

#define GLOAD16(gsrc, ldst) \
  __builtin_amdgcn_global_load_lds((const __attribute__((address_space(1))) void*)(gsrc), \
                                   (__attribute__((address_space(3))) void*)(ldst), 16, 0, 0)

// B=2, T=2048, D=1024, H=16, HD=64, 3D=3072, M=B*T=4096
// ws layout (bytes):
//   xbf  @ 0         : 4096*1024*2   = 8388608
//   Wt   @ 8388608   : 3072*1024*2   = 6291456
//   qkv  @ 14680064  : 4096*3072*2   = 25165824   (q columns pre-scaled by 0.125*log2e)
//   vT   @ 39845888  : 32*64*2048*2  = 8388608    (total 48234496)

// ---------------- kernel 1: x fp32->bf16 convert + W transpose (fused) ----------------
__global__ __launch_bounds__(256) void k_prep(const float* __restrict__ x,
                                              const float* __restrict__ W,
                                              u16* __restrict__ xbf,
                                              u16* __restrict__ Wt) {
  __shared__ __align__(16) u16 tile[64 * 72];
  int t = threadIdx.x;
  if (blockIdx.x < 2048) {
    int idx = blockIdx.x * 256 + t;                // 524288 threads * 8 elems
    const float4* xv = (const float4*)x;
    float4 a = xv[(size_t)idx * 2];
    float4 b = xv[(size_t)idx * 2 + 1];
    u16x8 o;
    o[0]=f2bf(a.x); o[1]=f2bf(a.y); o[2]=f2bf(a.z); o[3]=f2bf(a.w);
    o[4]=f2bf(b.x); o[5]=f2bf(b.y); o[6]=f2bf(b.z); o[7]=f2bf(b.w);
    *(u16x8*)(xbf + (size_t)idx * 8) = o;
    return;
  }
  int bid = blockIdx.x - 2048;
  int bk = bid & 15, bn = bid >> 4;                // 16 k-tiles x 48 n-tiles
  int k0 = bk * 64, n0 = bn * 64;
  #pragma unroll
  for (int r = 0; r < 4; r++) {
    int id = r * 256 + t;                          // 0..1023
    int kl = id >> 4;
    int c  = (id & 15) * 4;
    float4 v = *(const float4*)(W + (size_t)(k0 + kl) * 3072 + n0 + c);
    u16x4 o; o[0]=f2bf(v.x); o[1]=f2bf(v.y); o[2]=f2bf(v.z); o[3]=f2bf(v.w);
    *(u16x4*)(tile + kl * 72 + c) = o;
  }
  __syncthreads();
  #pragma unroll
  for (int r = 0; r < 2; r++) {
    int id = r * 256 + t;                          // 0..511
    int nl = id >> 3;
    int w  = id & 7;                               // 16B chunk = 8 k
    u16x8 o;
    #pragma unroll
    for (int i = 0; i < 8; i++) o[i] = tile[(w * 8 + i) * 72 + nl];
    *(u16x8*)(Wt + (size_t)(n0 + nl) * 1024 + k0 + w * 8) = o;
  }
}

// ------- kernel 2: qkv = xbf @ Wt^T + b  (bf16 MFMA, 128x192x64 tiles) -------
// 4 waves (2M x 2N), wave = 64x96 (acc 4x6). BK=64: per-phase compute ~500+ cyc
// so the 1-tile staging lookahead drains latency-free; 16 barriers total.
// LDS rows are 128B (8 units of 16B, bank-aligned) -> full 8-unit XOR swizzle
// u ^= row&7. 512 blocks = 2/CU. q cols pre-scaled by 0.125*log2e; v cols
// dual-written transposed into vT[b][h][d][t].
__global__ __launch_bounds__(256, 2) void k_gemm_qkv(const u16* __restrict__ xbf,
                                                     const u16* __restrict__ wt,
                                                     const float* __restrict__ bias,
                                                     u16* __restrict__ qkv,
                                                     u16* __restrict__ vT) {
  __shared__ __align__(16) u16 As[2 * 128 * 64];   // 32 KB (2 bufs x 16KB)
  __shared__ __align__(16) u16 Bs[2 * 192 * 64];   // 48 KB (2 bufs x 24KB)
  int wg = blockIdx.x;
  int swz = (wg & 7) * 64 + (wg >> 3);             // XCD-aware, bijective (512 = 8*64)
  int mt = swz >> 4, nt = swz & 15;                // 32 m-tiles x 16 n-tiles
  int m0 = mt * 128, n0 = nt * 192;
  int t = threadIdx.x;                             // 0..255
  int lane = t & 63, wid = t >> 6;
  int wm = wid >> 1, wn = wid & 1;
  int g = lane >> 4, li = lane & 15;

  f32x4 acc[4][6];
  #pragma unroll
  for (int i = 0; i < 4; i++)
    #pragma unroll
    for (int j = 0; j < 6; j++) acc[i][j] = (f32x4){0.f, 0.f, 0.f, 0.f};

  // staging: 128B rows = 8 units; phys unit w holds global unit w^(row&7)
  auto stage = [&](int kt, int buf) {
    char* ad = (char*)As + buf * 16384;
    char* bd = (char*)Bs + buf * 24576;
    #pragma unroll
    for (int i = 0; i < 4; i++) {
      int p = t + i * 256;                         // A: 128 rows x 8 units = 1024
      int row = p >> 3, ug = (p & 7) ^ (row & 7);
      GLOAD16(xbf + (size_t)(m0 + row) * 1024 + kt * 64 + ug * 8, ad + p * 16);
    }
    #pragma unroll
    for (int i = 0; i < 6; i++) {
      int p = t + i * 256;                         // B: 192 rows x 8 units = 1536
      int row = p >> 3, ug = (p & 7) ^ (row & 7);
      GLOAD16(wt + (size_t)(n0 + row) * 1024 + kt * 64 + ug * 8, bd + p * 16);
    }
  };

  stage(0, 0);
  for (int kt = 0; kt < 16; ++kt) {
    __syncthreads();                               // drains tile-kt loads (issued 1 tile ago)
    if (kt < 15) stage(kt + 1, (kt & 1) ^ 1);
    const char* ab = (const char*)As + (kt & 1) * 16384;
    const char* bb = (const char*)Bs + (kt & 1) * 24576;

    #pragma unroll
    for (int kk = 0; kk < 2; ++kk) {               // two K=32 halves of the 128B row
      bf16x8 af[4], bfr[6];
      #pragma unroll
      for (int mi = 0; mi < 4; mi++) {
        int row = wm * 64 + mi * 16 + li;
        int u = (kk * 4 + g) ^ (row & 7);
        af[mi] = *(const bf16x8*)(ab + row * 128 + u * 16);
      }
      #pragma unroll
      for (int ni = 0; ni < 6; ni++) {
        int row = wn * 96 + ni * 16 + li;
        int u = (kk * 4 + g) ^ (row & 7);
        bfr[ni] = *(const bf16x8*)(bb + row * 128 + u * 16);
      }
      __builtin_amdgcn_s_setprio(1);
      #pragma unroll
      for (int mi = 0; mi < 4; mi++)
        #pragma unroll
        for (int ni = 0; ni < 6; ni++)
          acc[mi][ni] = __builtin_amdgcn_mfma_f32_16x16x32_bf16(af[mi], bfr[ni], acc[mi][ni], 0, 0, 0);
      __builtin_amdgcn_s_setprio(0);
    }
  }

  // epilogue: +bias, scale q-cols, ->bf16; q/k cols -> qkv; v cols -> vT transposed
  int b = m0 >> 11;              // batch (M-tile never crosses batch: 2048%128==0)
  int tbase = m0 & 2047;
  #pragma unroll
  for (int ni = 0; ni < 6; ni++) {
    int col = n0 + wn * 96 + ni * 16 + li;
    float bv = bias[col];
    float sc = (col < 1024) ? 0.18033688011112042f : 1.0f;  // 0.125*log2(e) on q
    #pragma unroll
    for (int mi = 0; mi < 4; mi++) {
      int trow = tbase + wm * 64 + mi * 16 + g * 4;
      if (col < 2048) {
        #pragma unroll
        for (int j = 0; j < 4; j++) {
          float v = (acc[mi][ni][j] + bv) * sc;
          qkv[(size_t)(b * 2048 + trow + j) * 3072 + col] = f2bf(v);
        }
      } else {
        u16x4 o;
        #pragma unroll
        for (int j = 0; j < 4; j++) o[j] = f2bf(acc[mi][ni][j] + bv);
        // vT[b][h][d][t] with h*64+d = col-2048; 4 consecutive t
        *(u16x4*)(vT + ((size_t)(b * 1024 + (col - 2048))) * 2048 + trow) = o;
      }
    }
  }
}

// ------- kernel 3: flash attention, 2-wave blocks, 4 blocks/CU -------
// 64 q/block (32 q/wave), 64-key phases, 32KB LDS K/V double-buffer.
// bid decode puts all 32 q-tiles of a head on one XCD (bid%8 = bh%8) so K/V
// stay L2-resident. Permuted-key K staging (P packs lane-locally, V reads are
// single swizzled b128), bare v_exp_f32, lsum on the MFMA pipe (all-ones A).
// 4 desynchronized blocks/CU overlap MFMA/VALU/LDS phases across blocks.
__global__ __launch_bounds__(128, 4) void k_attn(const u16* __restrict__ qkv,
                                                 const u16* __restrict__ vT,
                                                 float* __restrict__ out) {
  // LDS bytes: K0 @0, K1 @8192, V0 @16384, V1 @24576. Epilogue reuses [0,16384).
  __shared__ __align__(16) u16 smem[16384];        // 32 KB
  int bid = blockIdx.x;
  int bh = bid & 31, qt = bid >> 5;                // 32 bh x 32 q-tiles (64 q)
  int b = bh >> 4, h = bh & 15;
  int qbase = qt * 64;
  int t = threadIdx.x, lane = t & 63, wave = t >> 6;  // wave in {0,1}
  int g = lane >> 4, li = lane & 15;

  // Q fragments: 2 x 16 q-rows per wave (pre-scaled by 0.125*log2e in GEMM)
  size_t qrowa = (size_t)(b * 2048 + qbase + wave * 32 + li) * 3072 + h * 64;
  bf16x8 qa0 = *(const bf16x8*)(qkv + qrowa + g * 8);
  bf16x8 qa1 = *(const bf16x8*)(qkv + qrowa + 32 + g * 8);
  bf16x8 qb0 = *(const bf16x8*)(qkv + qrowa + 16 * 3072 + g * 8);
  bf16x8 qb1 = *(const bf16x8*)(qkv + qrowa + 16 * 3072 + 32 + g * 8);

  // all-ones bf16 A-fragment for MFMA-side lsum
  u16x8 ob;
  #pragma unroll
  for (int i = 0; i < 8; i++) ob[i] = 0x3F80;
  bf16x8 ones = __builtin_bit_cast(bf16x8, ob);

  f32x4 o[2][4];
  #pragma unroll
  for (int f = 0; f < 2; f++)
    #pragma unroll
    for (int i = 0; i < 4; i++) o[f][i] = (f32x4){0.f, 0.f, 0.f, 0.f};
  f32x4 la = (f32x4){0.f, 0.f, 0.f, 0.f}, lb = la;  // lsum accumulators (MFMA)

  const u16* kbase_g = qkv + (size_t)(b * 2048) * 3072 + 1024 + h * 64;
  const u16* vbase_g = vT + (size_t)(bh * 64) * 2048;

  // staging slots (loop-invariant). K: 64 rows x 128B; V: 64 rows x 128B.
  // K rows permuted: kperm(r) = (r&32) | ((r&16)>>2) | (((r>>2)&3)<<3) | (r&3)
  int kRow[4], kUg[4], vRow[4], vUg[4];
  #pragma unroll
  for (int i = 0; i < 4; i++) {
    int p = t + i * 128;
    int kr = p >> 3;
    kRow[i] = (kr & 32) | ((kr & 16) >> 2) | (((kr >> 2) & 3) << 3) | (kr & 3);
    kUg[i] = (p & 7) ^ (kr & 7);
    vRow[i] = kr;
    vUg[i] = (p & 7) ^ (kr & 7);
  }

  auto stage = [&](int key0, int buf) {
    char* kd = (char*)smem + buf * 8192;
    char* vd_ = (char*)smem + 16384 + buf * 8192;
    #pragma unroll
    for (int i = 0; i < 4; i++) {
      int p = t + i * 128;
      GLOAD16(kbase_g + (size_t)(key0 + kRow[i]) * 3072 + kUg[i] * 8, kd + p * 16);
      GLOAD16(vbase_g + (size_t)vRow[i] * 2048 + key0 + vUg[i] * 8, vd_ + p * 16);
    }
  };

  stage(0, 0);
  asm volatile("s_waitcnt vmcnt(0)" ::: "memory");
  __syncthreads();

  #pragma unroll 2
  for (int ph = 0; ph < 32; ++ph) {
    int buf = ph & 1;
    const char* kb = (const char*)smem + buf * 8192;
    const char* vb = (const char*)smem + 16384 + buf * 8192;

    if (ph < 31) stage((ph + 1) * 64, buf ^ 1);    // lands by end-of-phase barrier

    // QK^T: S^T[key][q], both q-fragments share every K fragment read
    f32x4 sa[4], sb[4];
    int u0 = g ^ (li & 7);
    __builtin_amdgcn_s_setprio(1);
    #pragma unroll
    for (int st = 0; st < 4; ++st) {
      bf16x8 kf0 = *(const bf16x8*)(kb + (st * 16 + li) * 128 + u0 * 16);
      bf16x8 kf1 = *(const bf16x8*)(kb + (st * 16 + li) * 128 + (u0 ^ 4) * 16);
      f32x4 z = (f32x4){0.f, 0.f, 0.f, 0.f};
      sa[st] = __builtin_amdgcn_mfma_f32_16x16x32_bf16(kf0, qa0, z, 0, 0, 0);
      sa[st] = __builtin_amdgcn_mfma_f32_16x16x32_bf16(kf1, qa1, sa[st], 0, 0, 0);
      sb[st] = __builtin_amdgcn_mfma_f32_16x16x32_bf16(kf0, qb0, z, 0, 0, 0);
      sb[st] = __builtin_amdgcn_mfma_f32_16x16x32_bf16(kf1, qb1, sb[st], 0, 0, 0);
    }
    __builtin_amdgcn_s_setprio(0);

    // static softmax numerators: p = exp2(s) (q pre-scaled); bare v_exp_f32
    float pa[16], pbf[16];
    #pragma unroll
    for (int i = 0; i < 16; i++) pa[i] = fexp2(sa[i >> 2][i & 3]);
    #pragma unroll
    for (int i = 0; i < 16; i++) pbf[i] = fexp2(sb[i >> 2][i & 3]);

    // pack P fragments: kperm makes elem e of chunk c = physical key c*32+g*8+e
    bf16x8 pba[2], pbb[2];
    #pragma unroll
    for (int c = 0; c < 2; c++)
      #pragma unroll
      for (int e = 0; e < 8; e++) {
        pba[c][e] = (__bf16)pa[c * 8 + e];
        pbb[c][e] = (__bf16)pbf[c * 8 + e];
      }

    // lsum on the MFMA pipe + PV (V fragment shared by both q-frags)
    __builtin_amdgcn_s_setprio(1);
    la = __builtin_amdgcn_mfma_f32_16x16x32_bf16(ones, pba[0], la, 0, 0, 0);
    la = __builtin_amdgcn_mfma_f32_16x16x32_bf16(ones, pba[1], la, 0, 0, 0);
    lb = __builtin_amdgcn_mfma_f32_16x16x32_bf16(ones, pbb[0], lb, 0, 0, 0);
    lb = __builtin_amdgcn_mfma_f32_16x16x32_bf16(ones, pbb[1], lb, 0, 0, 0);
    #pragma unroll
    for (int c = 0; c < 2; c++) {
      int uc = c * 4 + g;
      #pragma unroll
      for (int dt = 0; dt < 4; dt++) {
        int d = dt * 16 + li;
        bf16x8 vf = *(const bf16x8*)(vb + d * 128 + ((uc ^ (d & 7)) << 4));
        o[0][dt] = __builtin_amdgcn_mfma_f32_16x16x32_bf16(vf, pba[c], o[0][dt], 0, 0, 0);
        o[1][dt] = __builtin_amdgcn_mfma_f32_16x16x32_bf16(vf, pbb[c], o[1][dt], 0, 0, 0);
      }
    }
    __builtin_amdgcn_s_setprio(0);

    __syncthreads();   // drains vmcnt (next-phase stage) + lgkm; one barrier per 64 keys
  }

  // epilogue: every lane already holds its q-column's full lsum in la[0]/lb[0]
  float inva = 1.0f / la[0], invb = 1.0f / lb[0];
  #pragma unroll
  for (int f = 0; f < 2; f++) {
    float inv = f ? invb : inva;
    int ql = wave * 32 + f * 16 + li;
    #pragma unroll
    for (int dt = 0; dt < 4; dt++) {
      int u = dt * 4 + g;
      int up = u ^ (ql & 7);
      f32x4 v = o[f][dt] * inv;
      *(f32x4*)((char*)smem + ql * 256 + up * 16) = v;
    }
  }
  __syncthreads();
  int ql = t >> 1, seg = t & 1;
  size_t obase = (size_t)(b * 2048 + qbase + ql) * 1024 + h * 64;
  #pragma unroll
  for (int i = 0; i < 8; i++) {
    int u = seg * 8 + i;
    int up = u ^ (ql & 7);
    f32x4 v = *(const f32x4*)((const char*)smem + ql * 256 + up * 16);
    *(f32x4*)(out + obase + u * 4) = v;
  }
}

extern "C" void kernel_launch(void* const* d_in, const int* in_sizes, int n_in,
                              void* d_out, int out_size, void* d_ws, size_t ws_size,
                              hipStream_t stream) {
  const float* x    = (const float*)d_in[0];
  const float* W    = (const float*)d_in[1];
  const float* bias = (const float*)d_in[2];
  float* out = (float*)d_out;
  char* ws = (char*)d_ws;
  u16* xbf = (u16*)(ws + 0);
  u16* wt  = (u16*)(ws + 8388608);
  u16* qkv = (u16*)(ws + 14680064);
  u16* vt  = (u16*)(ws + 39845888);

  k_prep<<<2816, 256, 0, stream>>>(x, W, xbf, wt);
  k_gemm_qkv<<<512, 256, 0, stream>>>(xbf, wt, bias, qkv, vt);
  k_attn<<<1024, 128, 0, stream>>>(qkv, vt, out);
}

// Round 8
// 81.763 us; speedup vs baseline: 1.2392x; 1.1392x over previous
//
#include <hip/hip_runtime.h>
#include <cstdint>

typedef unsigned short u16;
typedef __bf16 bf16x8 __attribute__((ext_vector_type(8)));
typedef float f32x4 __attribute__((ext_vector_type(4)));
typedef u16 u16x4 __attribute__((ext_vector_type(4)));
typedef u16 u16x8 __attribute__((ext_vector_type(8)));

static __device__ __forceinline__ u16 f2bf(float f) {
  return __builtin_bit_cast(u16, (__bf16)f);
}
static __device__ __forceinline__ float fexp2(float x) {
  float r;
  asm("v_exp_f32 %0, %1" : "=v"(r) : "v"(x));   // bare 2^x, 1 instr; exact for |x|<8
  return r;
}

#define GLOAD16(gsrc, ldst) \
  __builtin_amdgcn_global_load_lds((const __attribute__((address_space(1))) void*)(gsrc), \
                                   (__attribute__((address_space(3))) void*)(ldst), 16, 0, 0)

// B=2, T=2048, D=1024, H=16, HD=64, 3D=3072, M=B*T=4096
// ws layout (bytes):
//   xbf  @ 0         : 4096*1024*2   = 8388608
//   Wt   @ 8388608   : 3072*1024*2   = 6291456
//   qkv  @ 14680064  : 4096*3072*2   = 25165824   (q columns pre-scaled by 0.125*log2e)
//   vT   @ 39845888  : 32*64*2048*2  = 8388608    (total 48234496)

// ---------------- kernel 1: x fp32->bf16 convert + W transpose (fused) ----------------
__global__ __launch_bounds__(256) void k_prep(const float* __restrict__ x,
                                              const float* __restrict__ W,
                                              u16* __restrict__ xbf,
                                              u16* __restrict__ Wt) {
  __shared__ __align__(16) u16 tile[64 * 72];
  int t = threadIdx.x;
  if (blockIdx.x < 2048) {
    int idx = blockIdx.x * 256 + t;                // 524288 threads * 8 elems
    const float4* xv = (const float4*)x;
    float4 a = xv[(size_t)idx * 2];
    float4 b = xv[(size_t)idx * 2 + 1];
    u16x8 o;
    o[0]=f2bf(a.x); o[1]=f2bf(a.y); o[2]=f2bf(a.z); o[3]=f2bf(a.w);
    o[4]=f2bf(b.x); o[5]=f2bf(b.y); o[6]=f2bf(b.z); o[7]=f2bf(b.w);
    *(u16x8*)(xbf + (size_t)idx * 8) = o;
    return;
  }
  int bid = blockIdx.x - 2048;
  int bk = bid & 15, bn = bid >> 4;                // 16 k-tiles x 48 n-tiles
  int k0 = bk * 64, n0 = bn * 64;
  #pragma unroll
  for (int r = 0; r < 4; r++) {
    int id = r * 256 + t;                          // 0..1023
    int kl = id >> 4;
    int c  = (id & 15) * 4;
    float4 v = *(const float4*)(W + (size_t)(k0 + kl) * 3072 + n0 + c);
    u16x4 o; o[0]=f2bf(v.x); o[1]=f2bf(v.y); o[2]=f2bf(v.z); o[3]=f2bf(v.w);
    *(u16x4*)(tile + kl * 72 + c) = o;
  }
  __syncthreads();
  #pragma unroll
  for (int r = 0; r < 2; r++) {
    int id = r * 256 + t;                          // 0..511
    int nl = id >> 3;
    int w  = id & 7;                               // 16B chunk = 8 k
    u16x8 o;
    #pragma unroll
    for (int i = 0; i < 8; i++) o[i] = tile[(w * 8 + i) * 72 + nl];
    *(u16x8*)(Wt + (size_t)(n0 + nl) * 1024 + k0 + w * 8) = o;
  }
}

// ------- kernel 2: qkv = xbf @ Wt^T + b  (bf16 MFMA, 128x192x64 tiles) -------
// 4 waves (2M x 2N), wave = 64x96 (acc 4x6). BK=64, double-buffered LDS, one
// __syncthreads per K-tile, 1-tile staging lookahead. 128B LDS rows, 8-unit
// XOR swizzle u ^= row&7. 512 blocks = 2/CU. q cols pre-scaled by 0.125*log2e;
// v cols dual-written transposed into vT[b][h][d][t].
__global__ __launch_bounds__(256, 2) void k_gemm_qkv(const u16* __restrict__ xbf,
                                                     const u16* __restrict__ wt,
                                                     const float* __restrict__ bias,
                                                     u16* __restrict__ qkv,
                                                     u16* __restrict__ vT) {
  __shared__ __align__(16) u16 As[2 * 128 * 64];   // 32 KB (2 bufs x 16KB)
  __shared__ __align__(16) u16 Bs[2 * 192 * 64];   // 48 KB (2 bufs x 24KB)
  int wg = blockIdx.x;
  int swz = (wg & 7) * 64 + (wg >> 3);             // XCD-aware, bijective (512 = 8*64)
  int mt = swz >> 4, nt = swz & 15;                // 32 m-tiles x 16 n-tiles
  int m0 = mt * 128, n0 = nt * 192;
  int t = threadIdx.x;                             // 0..255
  int lane = t & 63, wid = t >> 6;
  int wm = wid >> 1, wn = wid & 1;
  int g = lane >> 4, li = lane & 15;

  f32x4 acc[4][6];
  #pragma unroll
  for (int i = 0; i < 4; i++)
    #pragma unroll
    for (int j = 0; j < 6; j++) acc[i][j] = (f32x4){0.f, 0.f, 0.f, 0.f};

  // staging: 128B rows = 8 units; phys unit w holds global unit w^(row&7)
  auto stage = [&](int kt, int buf) {
    char* ad = (char*)As + buf * 16384;
    char* bd = (char*)Bs + buf * 24576;
    #pragma unroll
    for (int i = 0; i < 4; i++) {
      int p = t + i * 256;                         // A: 128 rows x 8 units = 1024
      int row = p >> 3, ug = (p & 7) ^ (row & 7);
      GLOAD16(xbf + (size_t)(m0 + row) * 1024 + kt * 64 + ug * 8, ad + p * 16);
    }
    #pragma unroll
    for (int i = 0; i < 6; i++) {
      int p = t + i * 256;                         // B: 192 rows x 8 units = 1536
      int row = p >> 3, ug = (p & 7) ^ (row & 7);
      GLOAD16(wt + (size_t)(n0 + row) * 1024 + kt * 64 + ug * 8, bd + p * 16);
    }
  };

  stage(0, 0);
  for (int kt = 0; kt < 16; ++kt) {
    __syncthreads();                               // drains tile-kt loads (issued 1 tile ago)
    if (kt < 15) stage(kt + 1, (kt & 1) ^ 1);
    const char* ab = (const char*)As + (kt & 1) * 16384;
    const char* bb = (const char*)Bs + (kt & 1) * 24576;

    #pragma unroll
    for (int kk = 0; kk < 2; ++kk) {               // two K=32 halves of the 128B row
      bf16x8 af[4], bfr[6];
      #pragma unroll
      for (int mi = 0; mi < 4; mi++) {
        int row = wm * 64 + mi * 16 + li;
        int u = (kk * 4 + g) ^ (row & 7);
        af[mi] = *(const bf16x8*)(ab + row * 128 + u * 16);
      }
      #pragma unroll
      for (int ni = 0; ni < 6; ni++) {
        int row = wn * 96 + ni * 16 + li;
        int u = (kk * 4 + g) ^ (row & 7);
        bfr[ni] = *(const bf16x8*)(bb + row * 128 + u * 16);
      }
      __builtin_amdgcn_s_setprio(1);
      #pragma unroll
      for (int mi = 0; mi < 4; mi++)
        #pragma unroll
        for (int ni = 0; ni < 6; ni++)
          acc[mi][ni] = __builtin_amdgcn_mfma_f32_16x16x32_bf16(af[mi], bfr[ni], acc[mi][ni], 0, 0, 0);
      __builtin_amdgcn_s_setprio(0);
    }
  }

  // epilogue: +bias, scale q-cols, ->bf16; q/k cols -> qkv; v cols -> vT transposed
  int b = m0 >> 11;              // batch (M-tile never crosses batch: 2048%128==0)
  int tbase = m0 & 2047;
  #pragma unroll
  for (int ni = 0; ni < 6; ni++) {
    int col = n0 + wn * 96 + ni * 16 + li;
    float bv = bias[col];
    float sc = (col < 1024) ? 0.18033688011112042f : 1.0f;  // 0.125*log2(e) on q
    #pragma unroll
    for (int mi = 0; mi < 4; mi++) {
      int trow = tbase + wm * 64 + mi * 16 + g * 4;
      if (col < 2048) {
        #pragma unroll
        for (int j = 0; j < 4; j++) {
          float v = (acc[mi][ni][j] + bv) * sc;
          qkv[(size_t)(b * 2048 + trow + j) * 3072 + col] = f2bf(v);
        }
      } else {
        u16x4 o;
        #pragma unroll
        for (int j = 0; j < 4; j++) o[j] = f2bf(acc[mi][ni][j] + bv);
        // vT[b][h][d][t] with h*64+d = col-2048; 4 consecutive t
        *(u16x4*)(vT + ((size_t)(b * 1024 + (col - 2048))) * 2048 + trow) = o;
      }
    }
  }
}

// ------- kernel 3: flash attention, 64 q/wave, in-block K-split -------
// Block = 4 waves x 64 q = 128 q; waves {0,1} do keys 0..1023, {2,3} do
// 1024..2047 (static softmax -> partials combine by ADDITION, no rescale).
// Each wave: 4 q-frags share every K/V b128 read (72 MFMA / 16 ds_read per
// 64-key tile). 64KB LDS = 2 bufs x {K 2x8KB | V 2x8KB}. Permuted-key K
// staging (P packs lane-locally, V reads single swizzled b128), bare
// v_exp_f32, lsum on the MFMA pipe. In-LDS combine epilogue; per-head XCD
// locality via bh = bid&31. 512 blocks = 2/CU, 8 waves/CU.
__global__ __launch_bounds__(256, 2) void k_attn(const u16* __restrict__ qkv,
                                                 const u16* __restrict__ vT,
                                                 float* __restrict__ out) {
  __shared__ __align__(16) u16 smem[32768];        // 64 KB
  int bid = blockIdx.x;
  int bh = bid & 31, qt = bid >> 5;                // 32 bh x 16 q-tiles (128 q)
  int b = bh >> 4, h = bh & 15;
  int qbase = qt * 128;
  int t = threadIdx.x, lane = t & 63, wave = t >> 6;
  int g = lane >> 4, li = lane & 15;
  int kvHalf = wave >> 1, qh = wave & 1;           // key-half, q-half

  // Q fragments: 4 x 16 q-rows per wave x 2 k-chunks (pre-scaled by 0.125*log2e)
  bf16x8 q[4][2];
  #pragma unroll
  for (int qf = 0; qf < 4; qf++) {
    size_t qrow = (size_t)(b * 2048 + qbase + qh * 64 + qf * 16 + li) * 3072 + h * 64;
    q[qf][0] = *(const bf16x8*)(qkv + qrow + g * 8);
    q[qf][1] = *(const bf16x8*)(qkv + qrow + 32 + g * 8);
  }

  // all-ones bf16 A-fragment for MFMA-side lsum
  u16x8 ob;
  #pragma unroll
  for (int i = 0; i < 8; i++) ob[i] = 0x3F80;
  bf16x8 ones = __builtin_bit_cast(bf16x8, ob);

  f32x4 o[4][4];                                   // O^T accum: [qf][dt]
  #pragma unroll
  for (int i = 0; i < 4; i++)
    #pragma unroll
    for (int j = 0; j < 4; j++) o[i][j] = (f32x4){0.f, 0.f, 0.f, 0.f};
  f32x4 la[4];
  #pragma unroll
  for (int i = 0; i < 4; i++) la[i] = (f32x4){0.f, 0.f, 0.f, 0.f};

  const u16* kbase_g = qkv + (size_t)(b * 2048) * 3072 + 1024 + h * 64;
  const u16* vbase_g = vT + (size_t)(bh * 64) * 2048;

  // staging indices (loop-invariant): p = t + i*256 in 0..1023 covers both
  // halves (p>>9) x 64 rows x 8 units. K rows permuted within each half:
  // kperm(r) = (r&32) | ((r&16)>>2) | (((r>>2)&3)<<3) | (r&3)
  int kR[4], kU[4];
  size_t vO[4];
  #pragma unroll
  for (int i = 0; i < 4; i++) {
    int p = t + i * 256;
    int hf = p >> 9, p9 = p & 511;
    int kr = p9 >> 3;
    kR[i] = hf * 1024 + ((kr & 32) | ((kr & 16) >> 2) | (((kr >> 2) & 3) << 3) | (kr & 3));
    kU[i] = (p9 & 7) ^ (kr & 7);
    int d = p9 >> 3, u = p9 & 7;
    vO[i] = (size_t)d * 2048 + hf * 1024 + ((u ^ (d & 7)) * 8);
  }

  auto stage = [&](int key0, int buf) {
    char* kd = (char*)smem + buf * 32768;          // K: [half][64 rows][128B]
    char* vd = kd + 16384;                         // V: [half][64 d-rows][128B]
    #pragma unroll
    for (int i = 0; i < 4; i++) {
      int p = t + i * 256;
      GLOAD16(kbase_g + (size_t)(key0 + kR[i]) * 3072 + kU[i] * 8, kd + p * 16);
      GLOAD16(vbase_g + vO[i] + key0, vd + p * 16);
    }
  };

  stage(0, 0);
  asm volatile("s_waitcnt vmcnt(0)" ::: "memory");
  __syncthreads();

  for (int ph = 0; ph < 16; ++ph) {
    const char* bufb = (const char*)smem + (ph & 1) * 32768;
    const char* kb = bufb + kvHalf * 8192;
    const char* vb = bufb + 16384 + kvHalf * 8192;

    if (ph < 15) stage((ph + 1) * 64, (ph & 1) ^ 1);  // lands by end-of-phase barrier

    // QK^T: S^T[key][q], all 4 q-frags share every K fragment read
    f32x4 s[4][4];                                 // [st][qf]
    int u0 = g ^ (li & 7);
    __builtin_amdgcn_s_setprio(1);
    #pragma unroll
    for (int st = 0; st < 4; ++st) {
      bf16x8 kf0 = *(const bf16x8*)(kb + (st * 16 + li) * 128 + u0 * 16);
      bf16x8 kf1 = *(const bf16x8*)(kb + (st * 16 + li) * 128 + (u0 ^ 4) * 16);
      #pragma unroll
      for (int qf = 0; qf < 4; qf++) {
        f32x4 z = (f32x4){0.f, 0.f, 0.f, 0.f};
        s[st][qf] = __builtin_amdgcn_mfma_f32_16x16x32_bf16(kf0, q[qf][0], z, 0, 0, 0);
        s[st][qf] = __builtin_amdgcn_mfma_f32_16x16x32_bf16(kf1, q[qf][1], s[st][qf], 0, 0, 0);
      }
    }
    __builtin_amdgcn_s_setprio(0);

    // static softmax numerators: p = exp2(s); pack (kperm -> lane-local keys)
    bf16x8 pb[4][2];
    #pragma unroll
    for (int qf = 0; qf < 4; qf++) {
      float p16[16];
      #pragma unroll
      for (int i = 0; i < 16; i++) p16[i] = fexp2(s[i >> 2][qf][i & 3]);
      #pragma unroll
      for (int c = 0; c < 2; c++)
        #pragma unroll
        for (int e = 0; e < 8; e++) pb[qf][c][e] = (__bf16)p16[c * 8 + e];
    }

    // lsum on the MFMA pipe + PV (V fragment shared by all 4 q-frags)
    __builtin_amdgcn_s_setprio(1);
    #pragma unroll
    for (int qf = 0; qf < 4; qf++) {
      la[qf] = __builtin_amdgcn_mfma_f32_16x16x32_bf16(ones, pb[qf][0], la[qf], 0, 0, 0);
      la[qf] = __builtin_amdgcn_mfma_f32_16x16x32_bf16(ones, pb[qf][1], la[qf], 0, 0, 0);
    }
    #pragma unroll
    for (int c = 0; c < 2; c++) {
      #pragma unroll
      for (int dt = 0; dt < 4; dt++) {
        int d = dt * 16 + li;
        bf16x8 vf = *(const bf16x8*)(vb + d * 128 + (((c * 4 + g) ^ (d & 7)) << 4));
        #pragma unroll
        for (int qf = 0; qf < 4; qf++)
          o[qf][dt] = __builtin_amdgcn_mfma_f32_16x16x32_bf16(vf, pb[qf][c], o[qf][dt], 0, 0, 0);
      }
    }
    __builtin_amdgcn_s_setprio(0);

    __syncthreads();   // drains vmcnt (next-phase stage) + lgkm; one barrier per 64 keys
  }

  // ---- in-LDS K-split combine (static softmax: partials ADD) ----
  float* pO = (float*)smem;                        // [128 q][64 d] f32, unit-swizzled
  float* pL = (float*)((char*)smem + 32768);       // [128] f32 lsum (half 1)
  if (kvHalf) {
    #pragma unroll
    for (int qf = 0; qf < 4; qf++) {
      int qq = qh * 64 + qf * 16 + li;
      #pragma unroll
      for (int dt = 0; dt < 4; dt++) {
        int u = dt * 4 + g;
        *(f32x4*)((char*)pO + qq * 256 + ((u ^ (qq & 7)) << 4)) = o[qf][dt];
      }
      if (g == 0) pL[qq] = la[qf][0];
    }
  }
  __syncthreads();
  if (!kvHalf) {
    #pragma unroll
    for (int qf = 0; qf < 4; qf++) {
      int qq = qh * 64 + qf * 16 + li;
      float inv = 1.0f / (la[qf][0] + pL[qq]);
      size_t orow = (size_t)(b * 2048 + qbase + qq) * 1024 + h * 64;
      #pragma unroll
      for (int dt = 0; dt < 4; dt++) {
        int u = dt * 4 + g;
        f32x4 p2 = *(const f32x4*)((const char*)pO + qq * 256 + ((u ^ (qq & 7)) << 4));
        f32x4 r = (o[qf][dt] + p2) * inv;
        *(f32x4*)(out + orow + u * 4) = r;         // 16B store, 64B/4-lane group
      }
    }
  }
}

extern "C" void kernel_launch(void* const* d_in, const int* in_sizes, int n_in,
                              void* d_out, int out_size, void* d_ws, size_t ws_size,
                              hipStream_t stream) {
  const float* x    = (const float*)d_in[0];
  const float* W    = (const float*)d_in[1];
  const float* bias = (const float*)d_in[2];
  float* out = (float*)d_out;
  char* ws = (char*)d_ws;
  u16* xbf = (u16*)(ws + 0);
  u16* wt  = (u16*)(ws + 8388608);
  u16* qkv = (u16*)(ws + 14680064);
  u16* vt  = (u16*)(ws + 39845888);

  k_prep<<<2816, 256, 0, stream>>>(x, W, xbf, wt);
  k_gemm_qkv<<<512, 256, 0, stream>>>(xbf, wt, bias, qkv, vt);
  k_attn<<<512, 256, 0, stream>>>(qkv, vt, out);
}